// Round 3
// baseline (549.266 us; speedup 1.0000x reference)
//
#include <hip/hip_runtime.h>
#include <cstdint>

using u64 = unsigned long long;
using u32 = unsigned int;

// ---------------------------------------------------------------------------
// Fused prep: BN constants for 5 layers + sign-packing of w2..w5.
// Thread space: [0,704) = BN elements, [704, 704+7488) = pack words.
// ---------------------------------------------------------------------------
struct PrepArgs {
  const float* bng[5]; const float* bnb[5]; const float* bnm[5]; const float* bnv[5];
  float* inv[5]; float* cc[5];
  const float* w[4];
  u64* wp[4]; u64* wz[4];
  u32* flags;   // one per packed layer
};

__global__ __launch_bounds__(256) void prep_all(PrepArgs a) {
  int i = blockIdx.x * 256 + threadIdx.x;
  if (i < 704) {
    const int off[6] = {0, 64, 192, 320, 512, 704};
    int l = 0;
    while (i >= off[l + 1]) ++l;
    int c = i - off[l];
    float inv = __fdiv_rn(a.bng[l][c], __fsqrt_rn(__fadd_rn(a.bnv[l][c], 1e-5f)));
    a.inv[l][c] = inv;
    a.cc[l][c] = __fsub_rn(a.bnb[l][c], __fmul_rn(a.bnm[l][c], inv));
    return;
  }
  int j = i - 704;
  if (j >= 7488) return;
  const int poff[5] = {0, 1152, 3456, 6912, 7488};
  const int ICt[4] = {64, 128, 128, 192};
  const int Kt[4]  = {9, 9, 9, 1};
  const int Wt[4]  = {1, 2, 2, 3};
  int l = 0;
  while (j >= poff[l + 1]) ++l;
  int idx = j - poff[l];
  int W = Wt[l], K = Kt[l], IC = ICt[l];
  int wi = idx % W;
  int rest = idx / W;
  int t = rest % K;
  int oc = rest / K;
  u64 p = 0, z = 0;
  int icbase = wi * 64;
  int nb = IC - icbase; if (nb > 64) nb = 64;
  const float* w = a.w[l];
  for (int b = 0; b < nb; ++b) {
    float f = w[((size_t)oc * IC + (icbase + b)) * K + t];
    if (f > 0.f) p |= (1ull << b);
    else if (f == 0.f) z |= (1ull << b);
  }
  a.wp[l][idx] = p;
  a.wz[l][idx] = z;
  if (z) atomicOr(a.flags + l, 1u);
}

// ---------------------------------------------------------------------------
// conv1: fp32 1->64ch 3x3 stride2 pad1 + bias + BN threshold -> bit-pack.
// lane = output channel (64 lanes = 64 ch). Weights in VGPRs, activations
// wave-uniform with stride-2 sliding window. Output word via __ballot.
// Grid: 128n * 64y blocks of 64 threads; each wave does one output row.
// ---------------------------------------------------------------------------
__global__ __launch_bounds__(64) void conv1_bin(
    const float* __restrict__ x, const float* __restrict__ w1, const float* __restrict__ b1,
    const float* __restrict__ inv1, const float* __restrict__ cc1,
    u64* __restrict__ a1p) {
  int blk = blockIdx.x;     // n*64 + y
  int y = blk & 63, n = blk >> 6;
  int lane = threadIdx.x;
  float W[9];
#pragma unroll
  for (int t = 0; t < 9; ++t) W[t] = w1[lane * 9 + t];
  float bias = b1[lane], iv = inv1[lane], cb = cc1[lane];
  const float* xin = x + (size_t)n * 16384;
  int iy = 2 * y - 1;
  bool r0 = iy >= 0;                 // rows iy+1, iy+2 always in [0,127]
  float c0[3], c1[3], c2[3];
  c2[0] = c2[1] = c2[2] = 0.f;       // col -1 (pad)
  for (int xo = 0; xo < 64; ++xo) {
    c0[0] = c2[0]; c0[1] = c2[1]; c0[2] = c2[2];
    int ix = 2 * xo;
    c1[0] = r0 ? xin[iy * 128 + ix] : 0.f;
    c1[1] = xin[(iy + 1) * 128 + ix];
    c1[2] = xin[(iy + 2) * 128 + ix];
    c2[0] = r0 ? xin[iy * 128 + ix + 1] : 0.f;
    c2[1] = xin[(iy + 1) * 128 + ix + 1];
    c2[2] = xin[(iy + 2) * 128 + ix + 1];
    float acc = bias;
    acc += c0[0] * W[0] + c1[0] * W[1] + c2[0] * W[2]
         + c0[1] * W[3] + c1[1] * W[4] + c2[1] * W[5]
         + c0[2] * W[6] + c1[2] * W[7] + c2[2] * W[8];
    float bnv = __fadd_rn(__fmul_rn(acc, iv), cb);
    u64 m = __ballot(bnv > 0.f);
    if (lane == 0) a1p[(size_t)blk * 64 + xo] = m;
  }
}

// ---------------------------------------------------------------------------
// Binarized 3x3 conv, lane = oc. Weights in VGPRs (loaded once), activations
// wave-uniform sliding-window (stride1 reuses 2/3 cols). pa slides per-col.
// Output bit assembled via __ballot, stored by lane 0.
// ---------------------------------------------------------------------------
template <int CINW, int OCW, int NSTRIP, int STRIDE, int IN_HW, int OUT_HW>
__global__ __launch_bounds__(64 * OCW * NSTRIP) void bconv(
    const u64* __restrict__ ain, const u64* __restrict__ wp, const u64* __restrict__ wz,
    const u32* __restrict__ flag, const float* __restrict__ inv, const float* __restrict__ cc,
    u64* __restrict__ aout) {
  constexpr int PIX = OUT_HW / NSTRIP;
  constexpr int K = 9 * CINW;
  constexpr int CW = 3 * CINW;   // words per input column
  int blk = blockIdx.x;          // n*OUT_HW + y
  int y = blk % OUT_HW;
  int n = blk / OUT_HW;
  int tid = threadIdx.x;
  int lane = tid & 63;
  int wv = tid >> 6;
  int ocw = wv % OCW;
  int strip = wv / OCW;
  int oc = ocw * 64 + lane;

  u64 W[K];
#pragma unroll
  for (int t = 0; t < K; ++t) W[t] = wp[(size_t)oc * K + t];
  float iv = inv[oc], cb = cc[oc];
  bool anyz = (*flag != 0u);
  const u64* wzrow = wz + (size_t)oc * K;

  const u64* base = ain + (size_t)n * IN_HW * IN_HW * CINW;
  int iy = STRIDE * y - 1;
  bool rok[3] = { iy >= 0, true, iy + 2 < IN_HW };

  u64 c0[CW], c1[CW], c2[CW];
  int p0 = 0, p1 = 0, p2 = 0;

  auto ldcol = [&](int ix, u64* c) -> int {
    int p = 0;
    if (ix < 0 || ix >= IN_HW) {
#pragma unroll
      for (int j = 0; j < CW; ++j) c[j] = 0;
      return 0;
    }
#pragma unroll
    for (int r = 0; r < 3; ++r)
#pragma unroll
      for (int w = 0; w < CINW; ++w) {
        u64 a = rok[r] ? base[((size_t)(iy + r) * IN_HW + ix) * CINW + w] : 0ull;
        c[r * CINW + w] = a;
        p += __popcll(a);
      }
    return p;
  };

  int x0 = strip * PIX;
  if (STRIDE == 1) {
    p0 = ldcol(x0 - 1, c0);
    p1 = ldcol(x0, c1);
  } else {
    p2 = ldcol(2 * x0 - 1, c2);
  }

  for (int i = 0; i < PIX; ++i) {
    int x = x0 + i;
    if (STRIDE == 1) {
      p2 = ldcol(x + 1, c2);
    } else {
#pragma unroll
      for (int j = 0; j < CW; ++j) c0[j] = c2[j];
      p0 = p2;
      p1 = ldcol(2 * x, c1);
      p2 = ldcol(2 * x + 1, c2);
    }
    int s = 0;
#pragma unroll
    for (int r = 0; r < 3; ++r)
#pragma unroll
      for (int w = 0; w < CINW; ++w) {
        s += __popcll(c0[r * CINW + w] & W[(r * 3 + 0) * CINW + w]);
        s += __popcll(c1[r * CINW + w] & W[(r * 3 + 1) * CINW + w]);
        s += __popcll(c2[r * CINW + w] & W[(r * 3 + 2) * CINW + w]);
      }
    int val = 2 * s - (p0 + p1 + p2);
    if (anyz) {             // essentially never taken (random fp weights)
      int z = 0;
      for (int r = 0; r < 3; ++r)
        for (int w = 0; w < CINW; ++w) {
          z += __popcll(c0[r * CINW + w] & wzrow[(r * 3 + 0) * CINW + w]);
          z += __popcll(c1[r * CINW + w] & wzrow[(r * 3 + 1) * CINW + w]);
          z += __popcll(c2[r * CINW + w] & wzrow[(r * 3 + 2) * CINW + w]);
        }
      val += z;
    }
    float bnv = __fadd_rn(__fmul_rn((float)val, iv), cb);
    u64 m = __ballot(bnv > 0.f);
    if (lane == 0) aout[((size_t)blk * OUT_HW + x) * OCW + ocw] = m;
    if (STRIDE == 1) {
#pragma unroll
      for (int j = 0; j < CW; ++j) { c0[j] = c1[j]; c1[j] = c2[j]; }
      p0 = p1; p1 = p2;
    }
  }
}

// ---------------------------------------------------------------------------
// conv5 (binarized 1x1, 192->192) + BN + ReLU + partial pool. lane = oc,
// weights in 3 registers, activations uniform. 8 chunks of 128 pixels.
// ---------------------------------------------------------------------------
#define NCH5 8
#define CH5 128
__global__ __launch_bounds__(192) void bconv5_pool(
    const u64* __restrict__ ain, const u64* __restrict__ wp, const u64* __restrict__ wz,
    const u32* __restrict__ flag, const float* __restrict__ inv, const float* __restrict__ cc,
    float* __restrict__ partial) {
  int n = blockIdx.x / NCH5, ch = blockIdx.x % NCH5;
  int oc = threadIdx.x;    // 192 threads = 3 waves
  u64 W0 = wp[oc * 3], W1 = wp[oc * 3 + 1], W2 = wp[oc * 3 + 2];
  bool anyz = (*flag != 0u);
  float iv = inv[oc], cb = cc[oc];
  const u64* base = ain + ((size_t)n * 1024 + ch * CH5) * 3;
  float acc = 0.f;
  for (int p = 0; p < CH5; ++p) {
    u64 a0 = base[p * 3], a1 = base[p * 3 + 1], a2 = base[p * 3 + 2];
    int s = __popcll(a0 & W0) + __popcll(a1 & W1) + __popcll(a2 & W2);
    int pa = __popcll(a0) + __popcll(a1) + __popcll(a2);
    int val = 2 * s - pa;
    if (anyz) val += __popcll(a0 & wz[oc * 3]) + __popcll(a1 & wz[oc * 3 + 1])
                   + __popcll(a2 & wz[oc * 3 + 2]);
    float bnv = __fadd_rn(__fmul_rn((float)val, iv), cb);
    acc += fmaxf(bnv, 0.f);
  }
  partial[((size_t)n * NCH5 + ch) * 192 + oc] = acc;
}

// Deterministic fixed-order reduce over the 8 chunks.
__global__ __launch_bounds__(256) void pool_reduce(
    const float* __restrict__ partial, float* __restrict__ pool) {
  int idx = blockIdx.x * 256 + threadIdx.x;   // 128*192 = 24576
  if (idx >= 128 * 192) return;
  int n = idx / 192, oc = idx % 192;
  float s = 0.f;
#pragma unroll
  for (int ch = 0; ch < NCH5; ++ch) s += partial[((size_t)n * NCH5 + ch) * 192 + oc];
  pool[idx] = s;
}

// ---------------------------------------------------------------------------
// Head: mean (sum/1024) -> conv6 (1x1, 192->12) + b6 -> FC -> softmax.
// ---------------------------------------------------------------------------
__global__ __launch_bounds__(128) void head(
    const float* __restrict__ pool,   // [128][192] sums over 1024 pixels
    const float* __restrict__ w6, const float* __restrict__ b6,
    const float* __restrict__ fw, const float* __restrict__ fb,
    float* __restrict__ out) {        // [128][12]
  int n = threadIdx.x;
  if (n >= 128) return;
  float h6[12];
  for (int oc = 0; oc < 12; ++oc) {
    float s = 0.f;
    for (int c = 0; c < 192; ++c) s += pool[n * 192 + c] * w6[oc * 192 + c];
    h6[oc] = b6[oc] + s * (1.0f / 1024.0f);
  }
  float lg[12];
  float mx = -1e30f;
  for (int j = 0; j < 12; ++j) {
    float s = fb[j];
    for (int k = 0; k < 12; ++k) s += h6[k] * fw[j * 12 + k];
    lg[j] = s;
    mx = fmaxf(mx, s);
  }
  float se = 0.f;
  for (int j = 0; j < 12; ++j) { lg[j] = expf(lg[j] - mx); se += lg[j]; }
  for (int j = 0; j < 12; ++j) out[n * 12 + j] = lg[j] / se;
}

// ---------------------------------------------------------------------------
// Launch
// ---------------------------------------------------------------------------
extern "C" void kernel_launch(void* const* d_in, const int* in_sizes, int n_in,
                              void* d_out, int out_size, void* d_ws, size_t ws_size,
                              hipStream_t stream) {
  const float* x   = (const float*)d_in[0];
  const float* w1  = (const float*)d_in[1];
  const float* b1  = (const float*)d_in[2];
  const float* w2  = (const float*)d_in[3];
  const float* w3  = (const float*)d_in[4];
  const float* w4  = (const float*)d_in[5];
  const float* w5  = (const float*)d_in[6];
  const float* w6  = (const float*)d_in[7];
  const float* b6  = (const float*)d_in[8];
  const float* fcw = (const float*)d_in[9];
  const float* fcb = (const float*)d_in[10];
  float* out = (float*)d_out;

  char* ws = (char*)d_ws;
  size_t off = 0;
  auto alloc = [&](size_t bytes) -> void* {
    void* p = ws + off;
    off += (bytes + 255) & ~(size_t)255;
    return p;
  };
  const int C[5] = {64, 128, 128, 192, 192};
  float* inv[5];
  float* cc[5];
  for (int l = 0; l < 5; ++l) {
    inv[l] = (float*)alloc(C[l] * 4);
    cc[l]  = (float*)alloc(C[l] * 4);
  }
  u64* wp2 = (u64*)alloc(128 * 9 * 1 * 8);
  u64* wz2 = (u64*)alloc(128 * 9 * 1 * 8);
  u64* wp3 = (u64*)alloc(128 * 9 * 2 * 8);
  u64* wz3 = (u64*)alloc(128 * 9 * 2 * 8);
  u64* wp4 = (u64*)alloc(192 * 9 * 2 * 8);
  u64* wz4 = (u64*)alloc(192 * 9 * 2 * 8);
  u64* wp5 = (u64*)alloc(192 * 1 * 3 * 8);
  u64* wz5 = (u64*)alloc(192 * 1 * 3 * 8);
  u32* flags = (u32*)alloc(4 * sizeof(u32));
  u64* a1p = (u64*)alloc((size_t)128 * 64 * 64 * 1 * 8);
  u64* a2p = (u64*)alloc((size_t)128 * 64 * 64 * 2 * 8);
  u64* a3p = (u64*)alloc((size_t)128 * 32 * 32 * 2 * 8);
  u64* a4p = (u64*)alloc((size_t)128 * 32 * 32 * 3 * 8);
  float* partial = (float*)alloc((size_t)128 * NCH5 * 192 * 4);
  float* pool = (float*)alloc((size_t)128 * 192 * 4);
  (void)ws_size; (void)n_in; (void)in_sizes; (void)out_size;

  hipMemsetAsync(flags, 0, 4 * sizeof(u32), stream);

  PrepArgs pa;
  for (int l = 0; l < 5; ++l) {
    pa.bng[l] = (const float*)d_in[11 + 4 * l + 0];
    pa.bnb[l] = (const float*)d_in[11 + 4 * l + 1];
    pa.bnm[l] = (const float*)d_in[11 + 4 * l + 2];
    pa.bnv[l] = (const float*)d_in[11 + 4 * l + 3];
    pa.inv[l] = inv[l];
    pa.cc[l]  = cc[l];
  }
  pa.w[0] = w2; pa.w[1] = w3; pa.w[2] = w4; pa.w[3] = w5;
  pa.wp[0] = wp2; pa.wp[1] = wp3; pa.wp[2] = wp4; pa.wp[3] = wp5;
  pa.wz[0] = wz2; pa.wz[1] = wz3; pa.wz[2] = wz4; pa.wz[3] = wz5;
  pa.flags = flags;
  prep_all<<<32, 256, 0, stream>>>(pa);

  // conv1 + bin: one wave per output row
  conv1_bin<<<128 * 64, 64, 0, stream>>>(x, w1, b1, inv[0], cc[0], a1p);

  // conv2: 64ch(1w) -> 128ch(2w), 64x64, stride 1.  2 oc-words x 2 strips
  bconv<1, 2, 2, 1, 64, 64><<<128 * 64, 256, 0, stream>>>(
      a1p, wp2, wz2, flags + 0, inv[1], cc[1], a2p);

  // conv3: 128ch(2w) -> 128ch(2w), 64->32, stride 2.  2 oc-words x 2 strips
  bconv<2, 2, 2, 2, 64, 32><<<128 * 32, 256, 0, stream>>>(
      a2p, wp3, wz3, flags + 1, inv[2], cc[2], a3p);

  // conv4: 128ch(2w) -> 192ch(3w), 32x32, stride 1.  3 oc-words x 1 strip
  bconv<2, 3, 1, 1, 32, 32><<<128 * 32, 192, 0, stream>>>(
      a3p, wp4, wz4, flags + 2, inv[3], cc[3], a4p);

  // conv5 (1x1) + bn5 + relu + partial sums, then deterministic reduce
  bconv5_pool<<<128 * NCH5, 192, 0, stream>>>(a4p, wp5, wz5, flags + 3, inv[4], cc[4], partial);
  pool_reduce<<<(128 * 192 + 255) / 256, 256, 0, stream>>>(partial, pool);

  // head: mean -> conv6 -> fc -> softmax
  head<<<1, 128, 0, stream>>>(pool, w6, b6, fcw, fcb, out);
}

// Round 4
// 344.157 us; speedup vs baseline: 1.5960x; 1.5960x over previous
//
#include <hip/hip_runtime.h>
#include <cstdint>

using u64 = unsigned long long;
using u32 = unsigned int;

// ---------------------------------------------------------------------------
// Fused prep: BN constants for 5 layers + sign-packing of w2..w5.
// Thread space: [0,704) = BN elements, [704, 704+7488) = pack words.
// wp layout per layer: [oc][tap t=kh*3+kw][word wi]  (row = 9*CINW u64)
// ---------------------------------------------------------------------------
struct PrepArgs {
  const float* bng[5]; const float* bnb[5]; const float* bnm[5]; const float* bnv[5];
  float* inv[5]; float* cc[5];
  const float* w[4];
  u64* wp[4]; u64* wz[4];
  u32* flags;   // one per packed layer
};

__global__ __launch_bounds__(256) void prep_all(PrepArgs a) {
  int i = blockIdx.x * 256 + threadIdx.x;
  if (i < 704) {
    const int off[6] = {0, 64, 192, 320, 512, 704};
    int l = 0;
    while (i >= off[l + 1]) ++l;
    int c = i - off[l];
    float inv = __fdiv_rn(a.bng[l][c], __fsqrt_rn(__fadd_rn(a.bnv[l][c], 1e-5f)));
    a.inv[l][c] = inv;
    a.cc[l][c] = __fsub_rn(a.bnb[l][c], __fmul_rn(a.bnm[l][c], inv));
    return;
  }
  int j = i - 704;
  if (j >= 7488) return;
  const int poff[5] = {0, 1152, 3456, 6912, 7488};
  const int ICt[4] = {64, 128, 128, 192};
  const int Kt[4]  = {9, 9, 9, 1};
  const int Wt[4]  = {1, 2, 2, 3};
  int l = 0;
  while (j >= poff[l + 1]) ++l;
  int idx = j - poff[l];
  int W = Wt[l], K = Kt[l], IC = ICt[l];
  int wi = idx % W;
  int rest = idx / W;
  int t = rest % K;
  int oc = rest / K;
  u64 p = 0, z = 0;
  int icbase = wi * 64;
  int nb = IC - icbase; if (nb > 64) nb = 64;
  const float* w = a.w[l];
  for (int b = 0; b < nb; ++b) {
    float f = w[((size_t)oc * IC + (icbase + b)) * K + t];
    if (f > 0.f) p |= (1ull << b);
    else if (f == 0.f) z |= (1ull << b);
  }
  a.wp[l][idx] = p;
  a.wz[l][idx] = z;
  if (z) atomicOr(a.flags + l, 1u);
}

// ---------------------------------------------------------------------------
// conv1: fp32 1->64ch 3x3 stride2 pad1 + bias + BN threshold -> bit-pack into
// PADDED layout [n][66 rows][68 cols], data at (y+1, x+1).
// lane = channel; activations uniform (s_load); ring-of-4 column window;
// ballot per pixel collected into lane x; one row store per wave.
// ---------------------------------------------------------------------------
__global__ __launch_bounds__(256) void conv1_bin(
    const float* __restrict__ x, const float* __restrict__ w1, const float* __restrict__ b1,
    const float* __restrict__ inv1, const float* __restrict__ cc1,
    u64* __restrict__ a1p) {
  int tid = threadIdx.x, lane = tid & 63;
  int rb = __builtin_amdgcn_readfirstlane(tid >> 6);
  int blk = blockIdx.x;           // 128*16
  int y = (blk % 16) * 4 + rb;
  int n = blk / 16;
  float W[9];
#pragma unroll
  for (int t = 0; t < 9; ++t) W[t] = w1[lane * 9 + t];
  float bias = b1[lane], iv = inv1[lane], cb = cc1[lane];
  const float* xr1 = x + (size_t)n * 16384 + (2 * y) * 128;   // row 2y
  const float* xr2 = xr1 + 128;                               // row 2y+1
  const float* xr0 = (y > 0) ? (xr1 - 128) : xr1;             // clamped row 2y-1
  bool r0 = (y > 0);
  float c[4][3];
  c[0][0] = c[0][1] = c[0][2] = 0.f;   // pcol 0 == input col -1 (pad)
  u64 rowm = 0;

#define LD1(IX, S)                                        \
  {                                                       \
    float v0 = xr0[IX]; if (!r0) v0 = 0.f;                \
    c[S][0] = v0; c[S][1] = xr1[IX]; c[S][2] = xr2[IX];   \
  }
#define PX1(XO, S0, S1, S2)                                          \
  {                                                                  \
    float acc = bias;                                                \
    acc += c[S0][0] * W[0] + c[S1][0] * W[1] + c[S2][0] * W[2]       \
         + c[S0][1] * W[3] + c[S1][1] * W[4] + c[S2][1] * W[5]       \
         + c[S0][2] * W[6] + c[S1][2] * W[7] + c[S2][2] * W[8];      \
    float bnv = __fadd_rn(__fmul_rn(acc, iv), cb);                   \
    u64 m = __ballot(bnv > 0.f);                                     \
    rowm = (lane == (XO)) ? m : rowm;                                \
  }

  for (int x0 = 0; x0 < 64; x0 += 2) {
    LD1(2 * x0 + 0, 1); LD1(2 * x0 + 1, 2); PX1(x0 + 0, 0, 1, 2);
    LD1(2 * x0 + 2, 3); LD1(2 * x0 + 3, 0); PX1(x0 + 1, 2, 3, 0);
  }
  a1p[((size_t)n * 66 + (y + 1)) * 68 + lane + 1] = rowm;
#undef LD1
#undef PX1
}

// ---------------------------------------------------------------------------
// Binarized 3x3 conv, lane = oc, weights in VGPRs. Input PADDED
// [n][IN_HW+2 rows][IN_HW+4 cols][CINW] (guards zero). Activation columns are
// wave-uniform -> SGPR window (ring of 4, compile-time slots); pa via scalar
// popcount. One ballot per pixel, one store per row per wave.
// OPAD=1: output padded layout [n][OUT+2][OUT+4][OCW]; OPAD=0: dense.
// ---------------------------------------------------------------------------
template <int CINW, int OCW, int STRIDE, int IN_HW, int OUT_HW, int RPB, int OPAD>
__global__ __launch_bounds__(64 * OCW * RPB) void bconv(
    const u64* __restrict__ ain, const u64* __restrict__ wp, const u64* __restrict__ wz,
    const u32* __restrict__ flag, const float* __restrict__ inv, const float* __restrict__ cc,
    u64* __restrict__ aout) {
  constexpr int IPW = IN_HW + 4;     // padded width
  constexpr int K = 9 * CINW;
  constexpr int CW = 3 * CINW;       // u64 per column
  constexpr int YPB = OUT_HW / RPB;
  int tid = threadIdx.x;
  int lane = tid & 63;
  int wv = __builtin_amdgcn_readfirstlane(tid >> 6);
  int ocw = wv % OCW, rblk = wv / OCW;
  int blk = blockIdx.x;
  int y = (blk % YPB) * RPB + rblk;
  int n = blk / YPB;
  int oc = ocw * 64 + lane;

  u64 W[K];
#pragma unroll
  for (int t = 0; t < K; ++t) W[t] = wp[(size_t)oc * K + t];
  float iv = inv[oc], cb = cc[oc];
  bool anyz = (*flag != 0u);

  const u64* base = ain + ((size_t)n * (IN_HW + 2) + STRIDE * y) * IPW * CINW;

  u64 col[4][CW];
  int pc[4];
  u64 rowm = 0;

#define LDC(PCOL, S)                                                     \
  {                                                                      \
    int _p = 0;                                                          \
    _Pragma("unroll") for (int r = 0; r < 3; ++r)                        \
      _Pragma("unroll") for (int w = 0; w < CINW; ++w) {                 \
        u64 _v = base[((size_t)r * IPW + (PCOL)) * CINW + w];            \
        col[S][r * CINW + w] = _v;                                       \
        _p += __popcll(_v);                                              \
      }                                                                  \
    pc[S] = _p;                                                          \
  }

#define PIXEL(XO, S0, S1, S2)                                                     \
  {                                                                               \
    int _s = 0;                                                                   \
    _Pragma("unroll") for (int r = 0; r < 3; ++r)                                 \
      _Pragma("unroll") for (int w = 0; w < CINW; ++w) {                          \
        _s += __popcll(col[S0][r * CINW + w] & W[(r * 3 + 0) * CINW + w]);        \
        _s += __popcll(col[S1][r * CINW + w] & W[(r * 3 + 1) * CINW + w]);        \
        _s += __popcll(col[S2][r * CINW + w] & W[(r * 3 + 2) * CINW + w]);        \
      }                                                                           \
    int _val = 2 * _s - (pc[S0] + pc[S1] + pc[S2]);                               \
    if (anyz) {                                                                   \
      const u64* _zr = wz + (size_t)oc * K;                                       \
      for (int r = 0; r < 3; ++r)                                                 \
        for (int w = 0; w < CINW; ++w) {                                          \
          _val += __popcll(col[S0][r * CINW + w] & _zr[(r * 3 + 0) * CINW + w]);  \
          _val += __popcll(col[S1][r * CINW + w] & _zr[(r * 3 + 1) * CINW + w]);  \
          _val += __popcll(col[S2][r * CINW + w] & _zr[(r * 3 + 2) * CINW + w]);  \
        }                                                                         \
    }                                                                             \
    float _bn = __fadd_rn(__fmul_rn((float)_val, iv), cb);                        \
    u64 _m = __ballot(_bn > 0.f);                                                 \
    rowm = (lane == (XO)) ? _m : rowm;                                            \
  }

  if (STRIDE == 1) {
    LDC(0, 0); LDC(1, 1);
    for (int x0 = 0; x0 < OUT_HW; x0 += 4) {
      LDC(x0 + 2, 2); PIXEL(x0 + 0, 0, 1, 2);
      LDC(x0 + 3, 3); PIXEL(x0 + 1, 1, 2, 3);
      LDC(x0 + 4, 0); PIXEL(x0 + 2, 2, 3, 0);
      LDC(x0 + 5, 1); PIXEL(x0 + 3, 3, 0, 1);
    }
  } else {
    LDC(0, 0);
    for (int x0 = 0; x0 < OUT_HW; x0 += 2) {
      LDC(2 * x0 + 1, 1); LDC(2 * x0 + 2, 2); PIXEL(x0 + 0, 0, 1, 2);
      LDC(2 * x0 + 3, 3); LDC(2 * x0 + 4, 0); PIXEL(x0 + 1, 2, 3, 0);
    }
  }
#undef LDC
#undef PIXEL

  if (OPAD) {
    size_t orow = ((size_t)n * (OUT_HW + 2) + (y + 1)) * (OUT_HW + 4);
    if (OUT_HW == 64 || lane < OUT_HW)
      aout[(orow + lane + 1) * OCW + ocw] = rowm;
  } else {
    if (OUT_HW == 64 || lane < OUT_HW)
      aout[(((size_t)n * OUT_HW + y) * OUT_HW + lane) * OCW + ocw] = rowm;
  }
}

// ---------------------------------------------------------------------------
// conv5 (binarized 1x1, 192->192) + BN + ReLU + partial pool. lane = oc,
// weights in registers; activations uniform (s_load), pa scalar.
// ---------------------------------------------------------------------------
#define NCH5 8
#define CH5 128
__global__ __launch_bounds__(192) void bconv5_pool(
    const u64* __restrict__ ain, const u64* __restrict__ wp, const u64* __restrict__ wz,
    const u32* __restrict__ flag, const float* __restrict__ inv, const float* __restrict__ cc,
    float* __restrict__ partial) {
  int n = blockIdx.x / NCH5, ch = blockIdx.x % NCH5;
  int oc = threadIdx.x;    // 192 threads
  u64 W0 = wp[oc * 3], W1 = wp[oc * 3 + 1], W2 = wp[oc * 3 + 2];
  bool anyz = (*flag != 0u);
  float iv = inv[oc], cb = cc[oc];
  const u64* base = ain + ((size_t)n * 1024 + ch * CH5) * 3;
  float acc = 0.f;
#pragma unroll 4
  for (int p = 0; p < CH5; ++p) {
    u64 a0 = base[p * 3], a1 = base[p * 3 + 1], a2 = base[p * 3 + 2];  // uniform
    int pa = __popcll(a0) + __popcll(a1) + __popcll(a2);               // scalar
    int s = __popcll(a0 & W0) + __popcll(a1 & W1) + __popcll(a2 & W2);
    int val = 2 * s - pa;
    if (anyz) val += __popcll(a0 & wz[oc * 3]) + __popcll(a1 & wz[oc * 3 + 1])
                   + __popcll(a2 & wz[oc * 3 + 2]);
    float bnv = __fadd_rn(__fmul_rn((float)val, iv), cb);
    acc += fmaxf(bnv, 0.f);
  }
  partial[((size_t)n * NCH5 + ch) * 192 + oc] = acc;
}

// Deterministic fixed-order reduce over the 8 chunks.
__global__ __launch_bounds__(256) void pool_reduce(
    const float* __restrict__ partial, float* __restrict__ pool) {
  int idx = blockIdx.x * 256 + threadIdx.x;   // 128*192 = 24576
  if (idx >= 128 * 192) return;
  int n = idx / 192, oc = idx % 192;
  float s = 0.f;
#pragma unroll
  for (int ch = 0; ch < NCH5; ++ch) s += partial[((size_t)n * NCH5 + ch) * 192 + oc];
  pool[idx] = s;
}

// ---------------------------------------------------------------------------
// Head: mean (sum/1024) -> conv6 (1x1, 192->12) + b6 -> FC -> softmax.
// ---------------------------------------------------------------------------
__global__ __launch_bounds__(128) void head(
    const float* __restrict__ pool, const float* __restrict__ w6,
    const float* __restrict__ b6, const float* __restrict__ fw,
    const float* __restrict__ fb, float* __restrict__ out) {
  int n = threadIdx.x;
  if (n >= 128) return;
  float h6[12];
  for (int oc = 0; oc < 12; ++oc) {
    float s = 0.f;
    for (int c = 0; c < 192; ++c) s += pool[n * 192 + c] * w6[oc * 192 + c];
    h6[oc] = b6[oc] + s * (1.0f / 1024.0f);
  }
  float lg[12];
  float mx = -1e30f;
  for (int j = 0; j < 12; ++j) {
    float s = fb[j];
    for (int k = 0; k < 12; ++k) s += h6[k] * fw[j * 12 + k];
    lg[j] = s;
    mx = fmaxf(mx, s);
  }
  float se = 0.f;
  for (int j = 0; j < 12; ++j) { lg[j] = expf(lg[j] - mx); se += lg[j]; }
  for (int j = 0; j < 12; ++j) out[n * 12 + j] = lg[j] / se;
}

// ---------------------------------------------------------------------------
// Launch
// ---------------------------------------------------------------------------
extern "C" void kernel_launch(void* const* d_in, const int* in_sizes, int n_in,
                              void* d_out, int out_size, void* d_ws, size_t ws_size,
                              hipStream_t stream) {
  const float* x   = (const float*)d_in[0];
  const float* w1  = (const float*)d_in[1];
  const float* b1  = (const float*)d_in[2];
  const float* w2  = (const float*)d_in[3];
  const float* w3  = (const float*)d_in[4];
  const float* w4  = (const float*)d_in[5];
  const float* w5  = (const float*)d_in[6];
  const float* w6  = (const float*)d_in[7];
  const float* b6  = (const float*)d_in[8];
  const float* fcw = (const float*)d_in[9];
  const float* fcb = (const float*)d_in[10];
  float* out = (float*)d_out;

  char* ws = (char*)d_ws;
  size_t off = 0;
  auto alloc = [&](size_t bytes) -> void* {
    void* p = ws + off;
    off += (bytes + 255) & ~(size_t)255;
    return p;
  };
  const int C[5] = {64, 128, 128, 192, 192};
  float* inv[5];
  float* cc[5];
  for (int l = 0; l < 5; ++l) {
    inv[l] = (float*)alloc(C[l] * 4);
    cc[l]  = (float*)alloc(C[l] * 4);
  }
  u64* wp2 = (u64*)alloc(128 * 9 * 1 * 8);
  u64* wz2 = (u64*)alloc(128 * 9 * 1 * 8);
  u64* wp3 = (u64*)alloc(128 * 9 * 2 * 8);
  u64* wz3 = (u64*)alloc(128 * 9 * 2 * 8);
  u64* wp4 = (u64*)alloc(192 * 9 * 2 * 8);
  u64* wz4 = (u64*)alloc(192 * 9 * 2 * 8);
  u64* wp5 = (u64*)alloc(192 * 1 * 3 * 8);
  u64* wz5 = (u64*)alloc(192 * 1 * 3 * 8);
  u32* flags = (u32*)alloc(4 * sizeof(u32));
  // Padded activation buffers: [n][H+2][W+4][CINW] u64, guards zeroed below.
  size_t a1_sz = (size_t)128 * 66 * 68 * 1 * 8;       // 4,595,712
  size_t a2_sz = (size_t)128 * 66 * 68 * 2 * 8;       // 9,191,424
  size_t a3_sz = (size_t)128 * 34 * 36 * 2 * 8;       // 2,506,752
  u64* a1p = (u64*)alloc(a1_sz);
  u64* a2p = (u64*)alloc(a2_sz);
  u64* a3p = (u64*)alloc(a3_sz);
  u64* a4p = (u64*)alloc((size_t)128 * 32 * 32 * 3 * 8);   // dense
  float* partial = (float*)alloc((size_t)128 * NCH5 * 192 * 4);
  float* pool = (float*)alloc((size_t)128 * 192 * 4);
  (void)ws_size; (void)n_in; (void)in_sizes; (void)out_size;

  hipMemsetAsync(flags, 0, 4 * sizeof(u32), stream);
  hipMemsetAsync(a1p, 0, a1_sz + a2_sz + a3_sz, stream);   // contiguous guards

  PrepArgs pa;
  for (int l = 0; l < 5; ++l) {
    pa.bng[l] = (const float*)d_in[11 + 4 * l + 0];
    pa.bnb[l] = (const float*)d_in[11 + 4 * l + 1];
    pa.bnm[l] = (const float*)d_in[11 + 4 * l + 2];
    pa.bnv[l] = (const float*)d_in[11 + 4 * l + 3];
    pa.inv[l] = inv[l];
    pa.cc[l]  = cc[l];
  }
  pa.w[0] = w2; pa.w[1] = w3; pa.w[2] = w4; pa.w[3] = w5;
  pa.wp[0] = wp2; pa.wp[1] = wp3; pa.wp[2] = wp4; pa.wp[3] = wp5;
  pa.wz[0] = wz2; pa.wz[1] = wz3; pa.wz[2] = wz4; pa.wz[3] = wz5;
  pa.flags = flags;
  prep_all<<<32, 256, 0, stream>>>(pa);

  // conv1: 4 rows per 256-thread block
  conv1_bin<<<128 * 16, 256, 0, stream>>>(x, w1, b1, inv[0], cc[0], a1p);

  // conv2: 64ch(1w)->128ch(2w), 64x64, stride1. 2 ocw x 2 rows, padded out.
  bconv<1, 2, 1, 64, 64, 2, 1><<<128 * 32, 256, 0, stream>>>(
      a1p, wp2, wz2, flags + 0, inv[1], cc[1], a2p);

  // conv3: 128ch(2w)->128ch(2w), 64->32, stride2. 2 ocw x 2 rows, padded out.
  bconv<2, 2, 2, 64, 32, 2, 1><<<128 * 16, 256, 0, stream>>>(
      a2p, wp3, wz3, flags + 1, inv[2], cc[2], a3p);

  // conv4: 128ch(2w)->192ch(3w), 32x32, stride1. 3 ocw x 1 row, dense out.
  bconv<2, 3, 1, 32, 32, 1, 0><<<128 * 32, 192, 0, stream>>>(
      a3p, wp4, wz4, flags + 2, inv[3], cc[3], a4p);

  // conv5 (1x1) + bn5 + relu + partial sums, then deterministic reduce
  bconv5_pool<<<128 * NCH5, 192, 0, stream>>>(a4p, wp5, wz5, flags + 3, inv[4], cc[4], partial);
  pool_reduce<<<(128 * 192 + 255) / 256, 256, 0, stream>>>(partial, pool);

  // head: mean -> conv6 -> fc -> softmax
  head<<<1, 128, 0, stream>>>(pool, w6, b6, fcw, fcb, out);
}

// Round 6
// 286.479 us; speedup vs baseline: 1.9173x; 1.2013x over previous
//
#include <hip/hip_runtime.h>
#include <cstdint>

using u64 = unsigned long long;
using u32 = unsigned int;

// ---------------------------------------------------------------------------
// Fused prep: BN constants + exact integer thresholds (layers 2-4) + packing.
// Thread space: [0,704) BN elements, [704, 704+7488) pack words.
// ---------------------------------------------------------------------------
struct PrepArgs {
  const float* bng[5]; const float* bnb[5]; const float* bnm[5]; const float* bnv[5];
  float* inv1; float* cc1; float* inv5; float* cc5;
  int* thr[3]; int* flp[3];          // layers 2,3,4 (int cutoff + flip mask)
  const float* w[4];
  u64* wp[4]; u64* wz[4];
  u32* flags;
};

__global__ __launch_bounds__(256) void prep_all(PrepArgs a) {
  int i = blockIdx.x * 256 + threadIdx.x;
  if (i < 704) {
    const int off[6] = {0, 64, 192, 320, 512, 704};
    int l = 0;
    while (i >= off[l + 1]) ++l;
    int c = i - off[l];
    float iv = __fdiv_rn(a.bng[l][c], __fsqrt_rn(__fadd_rn(a.bnv[l][c], 1e-5f)));
    float cb = __fsub_rn(a.bnb[l][c], __fmul_rn(a.bnm[l][c], iv));
    if (l == 0) { a.inv1[c] = iv; a.cc1[c] = cb; }
    else if (l == 4) { a.inv5[c] = iv; a.cc5[c] = cb; }
    else {
      // exact integer cutoff of the monotone predicate (val int, |val|<=1152)
      auto pred = [&](int v_) {
        return __fadd_rn(__fmul_rn((float)v_, iv), cb) > 0.f;
      };
      int Tx, fl;
      if (iv == 0.f) { Tx = pred(0) ? -100000 : 100000; fl = 0; }
      else if (iv > 0.f) {
        if (pred(-2048)) { Tx = -100000; fl = 0; }
        else if (!pred(2048)) { Tx = 100000; fl = 0; }
        else {
          int lo = -2048, hi = 2048;
          while (hi - lo > 1) { int md = (lo + hi) >> 1; if (pred(md)) hi = md; else lo = md; }
          Tx = hi; fl = 0;   // bit = val >= Tx
        }
      } else {
        if (pred(2048)) { Tx = -100000; fl = -1; }
        else if (!pred(-2048)) { Tx = 100000; fl = -1; }
        else {
          int lo = -2048, hi = 2048;
          while (hi - lo > 1) { int md = (lo + hi) >> 1; if (pred(md)) lo = md; else hi = md; }
          Tx = lo ^ -1; fl = -1;   // bit = val <= lo  <=>  (val^-1) >= (~lo)
        }
      }
      a.thr[l - 1][c] = Tx; a.flp[l - 1][c] = fl;
    }
    return;
  }
  int j = i - 704;
  if (j >= 7488) return;
  const int poff[5] = {0, 1152, 3456, 6912, 7488};
  const int ICt[4] = {64, 128, 128, 192};
  const int Kt[4]  = {9, 9, 9, 1};
  const int Wt[4]  = {1, 2, 2, 3};
  int l = 0;
  while (j >= poff[l + 1]) ++l;
  int idx = j - poff[l];
  int W = Wt[l], K = Kt[l], IC = ICt[l];
  int wi = idx % W;
  int rest = idx / W;
  int t = rest % K;
  int oc = rest / K;
  u64 p = 0, z = 0;
  int icbase = wi * 64;
  int nb = IC - icbase; if (nb > 64) nb = 64;
  const float* w = a.w[l];
  for (int b = 0; b < nb; ++b) {
    float f = w[((size_t)oc * IC + (icbase + b)) * K + t];
    if (f > 0.f) p |= (1ull << b);
    else if (f == 0.f) z |= (1ull << b);
  }
  a.wp[l][idx] = p;
  a.wz[l][idx] = z;
  if (z) atomicOr(a.flags + l, 1u);
}

// ---------------------------------------------------------------------------
// Pad fp32 input into [n][130][136] (zero borders; data at row+1, col+1).
// ---------------------------------------------------------------------------
__global__ __launch_bounds__(256) void pad_x(const float* __restrict__ x,
                                             float* __restrict__ xpad) {
  int idx = blockIdx.x * 256 + threadIdx.x;   // 128*128*128
  int c = idx & 127, r = (idx >> 7) & 127, n = idx >> 14;
  xpad[((size_t)n * 130 + r + 1) * 136 + c + 1] = x[idx];
}

// ---------------------------------------------------------------------------
// conv1: fp32 1->64ch 3x3 s2 p1 + bias + BN threshold -> bit-pack (padded out).
// lane = channel; activations via scalar-ring (3 x 4-col fp32 buffers,
// prefetch one step ahead, batched uniform loads).
// ---------------------------------------------------------------------------
__global__ __launch_bounds__(256) void conv1_bin(
    const float* __restrict__ xpad, const float* __restrict__ w1, const float* __restrict__ b1,
    const float* __restrict__ inv1, const float* __restrict__ cc1,
    u64* __restrict__ a1p) {
  int tid = threadIdx.x, lane = tid & 63;
  int rb = __builtin_amdgcn_readfirstlane(tid >> 6);
  int blk = blockIdx.x;                // 128*16
  int y = (blk % 16) * 4 + rb;
  int n = blk / 16;
  float W[9];
#pragma unroll
  for (int t = 0; t < 9; ++t) W[t] = w1[lane * 9 + t];
  float bias = b1[lane], iv = inv1[lane], cb = cc1[lane];
  const float* sb = xpad + ((size_t)n * 130 + 2 * y) * 136;   // window rows 2y..2y+2
  float A[12], B[12], C[12];
  u64 rowm = 0;
  int xb = 0;

#define FLD(BUF, POFF)                                     \
  _Pragma("unroll") for (int _r = 0; _r < 3; ++_r)         \
  _Pragma("unroll") for (int _j = 0; _j < 4; ++_j)         \
    BUF[_r * 4 + _j] = sb[_r * 136 + (POFF) + _j];
#define FPX(XO, B0F, C0, B1F, C1, B2F, C2) {                          \
  float acc = 0.f;                                                    \
  _Pragma("unroll") for (int _r = 0; _r < 3; ++_r)                    \
    acc += B0F[_r * 4 + (C0)] * W[_r * 3 + 0]                         \
         + B1F[_r * 4 + (C1)] * W[_r * 3 + 1]                         \
         + B2F[_r * 4 + (C2)] * W[_r * 3 + 2];                        \
  float h = __fadd_rn(acc, bias);                                     \
  float bnv = __fadd_rn(__fmul_rn(h, iv), cb);                        \
  u64 _m = __ballot(bnv > 0.f);                                       \
  rowm = (lane == (XO)) ? _m : rowm; }
#define FSTEP(BA, BB, BC, POFF, XB)  \
  FLD(BC, (POFF) + 8);               \
  FPX((XB), BA, 0, BA, 1, BA, 2);    \
  FPX((XB) + 1, BA, 2, BA, 3, BB, 0);

  FLD(A, 0); FLD(B, 4);
  for (int g = 0; g < 10; ++g) {
    FSTEP(A, B, C, 0, xb);
    FSTEP(B, C, A, 4, xb + 2);
    FSTEP(C, A, B, 8, xb + 4);
    sb += 12; xb += 6;
  }
  FSTEP(A, B, C, 0, xb);
  FSTEP(B, C, A, 4, xb + 2);
  a1p[((size_t)n * 66 + (y + 1)) * 68 + lane + 1] = rowm;
#undef FLD
#undef FPX
#undef FSTEP
}

// ---------------------------------------------------------------------------
// Binarized 3x3 conv. lane = oc (weights in VGPRs); activation columns in a
// 3-buffer scalar ring (2 cols/buffer), prefetch one step ahead, per-column
// popcounts deferred to consume time (SALU). Int-threshold epilogue:
// bit = ((2s - pa) ^ flip) >= Tx  (exact, from prep's binary search).
// ---------------------------------------------------------------------------
template <int CINW, int OCW, int STRIDE, int IN_HW, int OUT_HW, int RPB, int OPAD>
__global__ __launch_bounds__(64 * OCW * RPB) void bconv(
    const u64* __restrict__ ain, const u64* __restrict__ wp, const u64* __restrict__ wz,
    const u32* __restrict__ flag, const int* __restrict__ thr, const int* __restrict__ flp,
    u64* __restrict__ aout) {
  constexpr int IPW = IN_HW + 4;
  constexpr int K = 9 * CINW;
  int tid = threadIdx.x;
  int lane = tid & 63;
  int wv = __builtin_amdgcn_readfirstlane(tid >> 6);
  int ocw = wv % OCW, rblk = wv / OCW;
  int blk = blockIdx.x;
  constexpr int BPI = OUT_HW / RPB;
  int y = (blk % BPI) * RPB + rblk;
  int n = blk / BPI;
  int oc = ocw * 64 + lane;

  u64 W[K];
#pragma unroll
  for (int t = 0; t < K; ++t) W[t] = wp[(size_t)oc * K + t];
  int Tx = thr[oc], flip = flp[oc];
  bool anyz = (*flag != 0u);

  const u64* sb = ain + ((size_t)n * (IN_HW + 2) + STRIDE * y) * IPW * CINW;

  u64 A[6 * CINW], B[6 * CINW], C[6 * CINW];
  int pA0 = 0, pA1 = 0, pB0 = 0, pB1 = 0, pC0 = 0, pC1 = 0;
  u64 rowm = 0;
  int xb = 0;

#define LDB(BUF, POFF)                                      \
  _Pragma("unroll") for (int _r = 0; _r < 3; ++_r)          \
  _Pragma("unroll") for (int _j = 0; _j < 2 * CINW; ++_j)   \
    BUF[_r * 2 * CINW + _j] = sb[((size_t)_r * IPW + (POFF)) * CINW + _j];
#define PCP(BUF, p0, p1) {                                  \
  int _q0 = 0, _q1 = 0;                                     \
  _Pragma("unroll") for (int _r = 0; _r < 3; ++_r)          \
  _Pragma("unroll") for (int _w = 0; _w < CINW; ++_w) {     \
    _q0 += __popcll(BUF[_r * 2 * CINW + _w]);               \
    _q1 += __popcll(BUF[_r * 2 * CINW + CINW + _w]); }      \
  (p0) = _q0; (p1) = _q1; }
#define PIX(XO, BA, CA, BB, CB, BC, CC, PATOT) {                                        \
  int _s = 0;                                                                           \
  _Pragma("unroll") for (int _r = 0; _r < 3; ++_r)                                      \
  _Pragma("unroll") for (int _w = 0; _w < CINW; ++_w) {                                 \
    _s += __popcll(BA[(_r * 2 + (CA)) * CINW + _w] & W[(_r * 3 + 0) * CINW + _w]);      \
    _s += __popcll(BB[(_r * 2 + (CB)) * CINW + _w] & W[(_r * 3 + 1) * CINW + _w]);      \
    _s += __popcll(BC[(_r * 2 + (CC)) * CINW + _w] & W[(_r * 3 + 2) * CINW + _w]); }    \
  int _val = 2 * _s - (PATOT);                                                          \
  if (anyz) {                                                                           \
    const u64* _zr = wz + (size_t)oc * K;                                               \
    for (int _r = 0; _r < 3; ++_r) for (int _w = 0; _w < CINW; ++_w) {                  \
      _val += __popcll(BA[(_r * 2 + (CA)) * CINW + _w] & _zr[(_r * 3 + 0) * CINW + _w]);\
      _val += __popcll(BB[(_r * 2 + (CB)) * CINW + _w] & _zr[(_r * 3 + 1) * CINW + _w]);\
      _val += __popcll(BC[(_r * 2 + (CC)) * CINW + _w] & _zr[(_r * 3 + 2) * CINW + _w]); } } \
  u64 _m = __ballot((_val ^ flip) >= Tx);                                               \
  rowm = (lane == (XO)) ? _m : rowm; }
#define STEP1(BA, pa0, pa1, BB, pb0, pb1, BC, POFF, XB)         \
  LDB(BC, (POFF) + 4);                                          \
  PCP(BB, pb0, pb1);                                            \
  PIX((XB), BA, 0, BA, 1, BB, 0, (pa0) + (pa1) + (pb0));        \
  PIX((XB) + 1, BA, 1, BB, 0, BB, 1, (pa1) + (pb0) + (pb1));
#define STEP2(BA, pa0, pa1, BB, pb0, pb1, BC, POFF, XB)         \
  LDB(BC, (POFF) + 4);                                          \
  PCP(BB, pb0, pb1);                                            \
  PIX((XB), BA, 0, BA, 1, BB, 0, (pa0) + (pa1) + (pb0));

  LDB(A, 0); LDB(B, 2);
  PCP(A, pA0, pA1);
  constexpr int NSTEP = (STRIDE == 1) ? OUT_HW / 2 : OUT_HW;
  constexpr int NG = NSTEP / 3;
  constexpr int NT = NSTEP % 3;
  for (int g = 0; g < NG; ++g) {
    if constexpr (STRIDE == 1) {
      STEP1(A, pA0, pA1, B, pB0, pB1, C, 0, xb);
      STEP1(B, pB0, pB1, C, pC0, pC1, A, 2, xb + 2);
      STEP1(C, pC0, pC1, A, pA0, pA1, B, 4, xb + 4);
      xb += 6;
    } else {
      STEP2(A, pA0, pA1, B, pB0, pB1, C, 0, xb);
      STEP2(B, pB0, pB1, C, pC0, pC1, A, 2, xb + 1);
      STEP2(C, pC0, pC1, A, pA0, pA1, B, 4, xb + 2);
      xb += 3;
    }
    sb += 6 * CINW;
  }
  if constexpr (NT >= 1) {
    if constexpr (STRIDE == 1) { STEP1(A, pA0, pA1, B, pB0, pB1, C, 0, xb) }
    else { STEP2(A, pA0, pA1, B, pB0, pB1, C, 0, xb) }
  }
  if constexpr (NT >= 2) {
    if constexpr (STRIDE == 1) { STEP1(B, pB0, pB1, C, pC0, pC1, A, 2, xb + 2) }
    else { STEP2(B, pB0, pB1, C, pC0, pC1, A, 2, xb + 1) }
  }
#undef LDB
#undef PCP
#undef PIX
#undef STEP1
#undef STEP2

  u64 rowm2 = rowm;
  if constexpr (OPAD) {
    if (OUT_HW == 64 || lane < OUT_HW)
      aout[(((size_t)n * (OUT_HW + 2) + (y + 1)) * (OUT_HW + 4) + lane + 1) * OCW + ocw] = rowm2;
  } else {
    if (OUT_HW == 64 || lane < OUT_HW)
      aout[(((size_t)n * OUT_HW + y) * OUT_HW + lane) * OCW + ocw] = rowm2;
  }
}

// ---------------------------------------------------------------------------
// conv5 (binarized 1x1, 192->192) + BN + ReLU + partial pool.
// lane = oc; uniform activations via scalar ring (prefetch 2 px ahead).
// ---------------------------------------------------------------------------
#define NCH5 8
__global__ __launch_bounds__(192) void bconv5_pool(
    const u64* __restrict__ ain, const u64* __restrict__ wp, const u64* __restrict__ wz,
    const u32* __restrict__ flag, const float* __restrict__ inv5, const float* __restrict__ cc5,
    float* __restrict__ partial) {
  int n = blockIdx.x / NCH5, ch = blockIdx.x % NCH5;
  int oc = threadIdx.x;
  u64 W0 = wp[oc * 3], W1 = wp[oc * 3 + 1], W2 = wp[oc * 3 + 2];
  bool anyz = (*flag != 0u);
  float iv = inv5[oc], cb = cc5[oc];
  const u64* sb = ain + ((size_t)n * 1024 + ch * 128) * 3;
  u64 A0, A1, A2, B0, B1, B2, C0, C1, C2;
  float acc = 0.f;
#define LD5(P, a0_, a1_, a2_) { a0_ = sb[(P) * 3]; a1_ = sb[(P) * 3 + 1]; a2_ = sb[(P) * 3 + 2]; }
#define PX5(a0_, a1_, a2_) {                                                   \
  int _pa = __popcll(a0_) + __popcll(a1_) + __popcll(a2_);                     \
  int _s = __popcll(a0_ & W0) + __popcll(a1_ & W1) + __popcll(a2_ & W2);       \
  int _val = 2 * _s - _pa;                                                     \
  if (anyz) _val += __popcll(a0_ & wz[oc * 3]) + __popcll(a1_ & wz[oc * 3 + 1])\
                  + __popcll(a2_ & wz[oc * 3 + 2]);                            \
  float _b = __fadd_rn(__fmul_rn((float)_val, iv), cb);                        \
  acc += fmaxf(_b, 0.f); }
  LD5(0, A0, A1, A2); LD5(1, B0, B1, B2);
  for (int g = 0; g < 42; ++g) {
    LD5(2, C0, C1, C2); PX5(A0, A1, A2);
    LD5(3, A0, A1, A2); PX5(B0, B1, B2);
    LD5(4, B0, B1, B2); PX5(C0, C1, C2);
    sb += 9;
  }
  PX5(A0, A1, A2); PX5(B0, B1, B2);
  partial[((size_t)n * NCH5 + ch) * 192 + oc] = acc;
#undef LD5
#undef PX5
}

// ---------------------------------------------------------------------------
// Fused reduce + head: sum 8 chunks -> mean -> conv6 -> FC -> softmax.
// One block per image, 192 threads.
// ---------------------------------------------------------------------------
__global__ __launch_bounds__(192) void head2(
    const float* __restrict__ partial,  // [128][8][192]
    const float* __restrict__ w6, const float* __restrict__ b6,
    const float* __restrict__ fw, const float* __restrict__ fb,
    float* __restrict__ out) {          // [128][12]
  __shared__ float pool_s[192];
  __shared__ float h6s[12];
  __shared__ float lgs[12];
  int n = blockIdx.x, t = threadIdx.x;
  float s = 0.f;
#pragma unroll
  for (int ch = 0; ch < NCH5; ++ch) s += partial[((size_t)n * NCH5 + ch) * 192 + t];
  pool_s[t] = s;
  __syncthreads();
  if (t < 12) {
    float a = 0.f;
    for (int c = 0; c < 192; ++c) a += pool_s[c] * w6[t * 192 + c];
    h6s[t] = b6[t] + a * (1.0f / 1024.0f);
  }
  __syncthreads();
  if (t < 12) {
    float s2 = fb[t];
    for (int k = 0; k < 12; ++k) s2 += h6s[k] * fw[t * 12 + k];
    lgs[t] = s2;
  }
  __syncthreads();
  if (t == 0) {
    float mx = -1e30f;
    for (int j = 0; j < 12; ++j) mx = fmaxf(mx, lgs[j]);
    float e[12], se = 0.f;
    for (int j = 0; j < 12; ++j) { e[j] = expf(lgs[j] - mx); se += e[j]; }
    for (int j = 0; j < 12; ++j) out[n * 12 + j] = e[j] / se;
  }
}

// ---------------------------------------------------------------------------
// Launch
// ---------------------------------------------------------------------------
extern "C" void kernel_launch(void* const* d_in, const int* in_sizes, int n_in,
                              void* d_out, int out_size, void* d_ws, size_t ws_size,
                              hipStream_t stream) {
  const float* x   = (const float*)d_in[0];
  const float* w1  = (const float*)d_in[1];
  const float* b1  = (const float*)d_in[2];
  const float* w2  = (const float*)d_in[3];
  const float* w3  = (const float*)d_in[4];
  const float* w4  = (const float*)d_in[5];
  const float* w5  = (const float*)d_in[6];
  const float* w6  = (const float*)d_in[7];
  const float* b6  = (const float*)d_in[8];
  const float* fcw = (const float*)d_in[9];
  const float* fcb = (const float*)d_in[10];
  float* out = (float*)d_out;

  char* ws = (char*)d_ws;
  size_t off = 0;
  auto alloc = [&](size_t bytes) -> void* {
    void* p = ws + off;
    off += (bytes + 255) & ~(size_t)255;
    return p;
  };
  // Contiguous zero-init region first: xpad + padded activation buffers.
  size_t xp_sz = (size_t)128 * 130 * 136 * 4;          // 9,052,160
  size_t a1_sz = (size_t)128 * 66 * 68 * 1 * 8;        // 4,595,712
  size_t a2_sz = (size_t)128 * 66 * 68 * 2 * 8;        // 9,191,424
  size_t a3_sz = (size_t)128 * 34 * 36 * 2 * 8;        // 2,506,752
  float* xpad = (float*)alloc(xp_sz);
  u64* a1p = (u64*)alloc(a1_sz);
  u64* a2p = (u64*)alloc(a2_sz);
  u64* a3p = (u64*)alloc(a3_sz);
  size_t zero_sz = xp_sz + a1_sz + a2_sz + a3_sz;      // all 256-multiples
  u64* a4p = (u64*)alloc((size_t)128 * 32 * 32 * 3 * 8);
  float* partial = (float*)alloc((size_t)128 * NCH5 * 192 * 4);
  float* inv1 = (float*)alloc(64 * 4);
  float* cc1  = (float*)alloc(64 * 4);
  float* inv5 = (float*)alloc(192 * 4);
  float* cc5  = (float*)alloc(192 * 4);
  int* thr2 = (int*)alloc(128 * 4); int* flp2 = (int*)alloc(128 * 4);
  int* thr3 = (int*)alloc(128 * 4); int* flp3 = (int*)alloc(128 * 4);
  int* thr4 = (int*)alloc(192 * 4); int* flp4 = (int*)alloc(192 * 4);
  u64* wp2 = (u64*)alloc(128 * 9 * 1 * 8);
  u64* wz2 = (u64*)alloc(128 * 9 * 1 * 8);
  u64* wp3 = (u64*)alloc(128 * 9 * 2 * 8);
  u64* wz3 = (u64*)alloc(128 * 9 * 2 * 8);
  u64* wp4 = (u64*)alloc(192 * 9 * 2 * 8);
  u64* wz4 = (u64*)alloc(192 * 9 * 2 * 8);
  u64* wp5 = (u64*)alloc(192 * 1 * 3 * 8);
  u64* wz5 = (u64*)alloc(192 * 1 * 3 * 8);
  u32* flags = (u32*)alloc(4 * sizeof(u32));
  (void)ws_size; (void)n_in; (void)in_sizes; (void)out_size;

  hipMemsetAsync(xpad, 0, zero_sz, stream);
  hipMemsetAsync(flags, 0, 4 * sizeof(u32), stream);

  PrepArgs pa;
  for (int l = 0; l < 5; ++l) {
    pa.bng[l] = (const float*)d_in[11 + 4 * l + 0];
    pa.bnb[l] = (const float*)d_in[11 + 4 * l + 1];
    pa.bnm[l] = (const float*)d_in[11 + 4 * l + 2];
    pa.bnv[l] = (const float*)d_in[11 + 4 * l + 3];
  }
  pa.inv1 = inv1; pa.cc1 = cc1; pa.inv5 = inv5; pa.cc5 = cc5;
  pa.thr[0] = thr2; pa.flp[0] = flp2;
  pa.thr[1] = thr3; pa.flp[1] = flp3;
  pa.thr[2] = thr4; pa.flp[2] = flp4;
  pa.w[0] = w2; pa.w[1] = w3; pa.w[2] = w4; pa.w[3] = w5;
  pa.wp[0] = wp2; pa.wp[1] = wp3; pa.wp[2] = wp4; pa.wp[3] = wp5;
  pa.wz[0] = wz2; pa.wz[1] = wz3; pa.wz[2] = wz4; pa.wz[3] = wz5;
  pa.flags = flags;
  prep_all<<<32, 256, 0, stream>>>(pa);

  pad_x<<<(128 * 128 * 128) / 256, 256, 0, stream>>>(x, xpad);

  // conv1: 4 rows per 256-thread block
  conv1_bin<<<128 * 16, 256, 0, stream>>>(xpad, w1, b1, inv1, cc1, a1p);

  // conv2: 64ch(1w)->128ch(2w), 64x64, stride1, padded out
  bconv<1, 2, 1, 64, 64, 2, 1><<<128 * 32, 256, 0, stream>>>(
      a1p, wp2, wz2, flags + 0, thr2, flp2, a2p);

  // conv3: 128ch(2w)->128ch(2w), 64->32, stride2, padded out
  bconv<2, 2, 2, 64, 32, 2, 1><<<128 * 16, 256, 0, stream>>>(
      a2p, wp3, wz3, flags + 1, thr3, flp3, a3p);

  // conv4: 128ch(2w)->192ch(3w), 32x32, stride1, dense out
  bconv<2, 3, 1, 32, 32, 1, 0><<<128 * 32, 192, 0, stream>>>(
      a3p, wp4, wz4, flags + 2, thr4, flp4, a4p);

  // conv5 (1x1) + bn5 + relu + partial sums
  bconv5_pool<<<128 * NCH5, 192, 0, stream>>>(a4p, wp5, wz5, flags + 3, inv5, cc5, partial);

  // fused reduce + conv6 + fc + softmax
  head2<<<128, 192, 0, stream>>>(partial, w6, b6, fcw, fcb, out);
}